// Round 15
// baseline (329.628 us; speedup 1.0000x reference)
//
#include <hip/hip_runtime.h>
#include <hip/hip_bf16.h>

typedef __attribute__((ext_vector_type(8))) short bf16x8;
typedef __attribute__((ext_vector_type(4))) float f32x4;
typedef unsigned short u16;

#define T_TOK 2048
#define HID 4096
#define NH 32
#define NKV 8
#define HD 128
#define QKVN 6144   // (NH + 2*NKV) * HD
#define KOFF 4096   // k column offset in qkv
#define VOFF 5120   // v column offset in qkv
#define ATTN_SCALE 0.08838834764831845f

static __device__ __forceinline__ float bf2f(u16 x) {
    union { float f; unsigned u; } v; v.u = ((unsigned)x) << 16; return v.f;
}
static __device__ __forceinline__ u16 f2bf(float f) {
    union { float f; unsigned u; } v; v.f = f;
    unsigned u = v.u;
    unsigned r = (u + 0x7fff + ((u >> 16) & 1)) >> 16;
    return (u16)r;
}

// async global->LDS, 16B per lane; LDS dest = WAVE-UNIFORM base (HW adds lane*16B)
static __device__ __forceinline__ void gload16(const u16* g, u16* l) {
    __builtin_amdgcn_global_load_lds((const __attribute__((address_space(1))) void*)g,
                                     (__attribute__((address_space(3))) void*)l, 16, 0, 0);
}

#define VMC(n) asm volatile("s_waitcnt vmcnt(%0)" :: "i"(n) : "memory")
#define LGKM0() asm volatile("s_waitcnt lgkmcnt(0)" ::: "memory")
#define BAR() __builtin_amdgcn_s_barrier()
#define SCHB() __builtin_amdgcn_sched_barrier(0)

// ---------------- elementwise f32 -> bf16 ----------------
__global__ __launch_bounds__(256) void convk(const float* __restrict__ in, u16* __restrict__ out) {
    int i = blockIdx.x * 256 + threadIdx.x;
    float4 v = ((const float4*)in)[i];
    ushort4 o;
    o.x = f2bf(v.x); o.y = f2bf(v.y); o.z = f2bf(v.z); o.w = f2bf(v.w);
    ((ushort4*)out)[i] = o;
}

// ---------------- transpose + convert: in f32 [R][C] -> out bf16 [C][R] ----------------
__global__ __launch_bounds__(256) void transpk(const float* __restrict__ in, u16* __restrict__ out,
                                               int R, int C) {
    __shared__ float tile[64][65];
    int c0 = blockIdx.x * 64, r0 = blockIdx.y * 64;
    int tid = threadIdx.x;
#pragma unroll
    for (int it = 0; it < 4; ++it) {
        int ci = it * 256 + tid;
        int r = ci >> 4, c4 = (ci & 15) * 4;
        float4 v = *(const float4*)&in[(size_t)(r0 + r) * C + c0 + c4];
        tile[r][c4 + 0] = v.x; tile[r][c4 + 1] = v.y; tile[r][c4 + 2] = v.z; tile[r][c4 + 3] = v.w;
    }
    __syncthreads();
#pragma unroll
    for (int it = 0; it < 4; ++it) {
        int ci = it * 256 + tid;
        int c = ci >> 4, rq = (ci & 15) * 4;
        ushort4 o;
        o.x = f2bf(tile[rq + 0][c]); o.y = f2bf(tile[rq + 1][c]);
        o.z = f2bf(tile[rq + 2][c]); o.w = f2bf(tile[rq + 3][c]);
        *(ushort4*)&out[(size_t)(c0 + c) * R + r0 + rq] = o;
    }
}

// ---------------- m201-style 256x256 GEMM (QKV): BK=64, 8 waves, per-wave 128x64 ----------------
// Interleaved frag assignment: wave wm reads A rows (mi&3)*32+wm*16 within A-half (mi>>2);
// wave wn reads B rows (nj&1)*64+wn*16 within B-half (nj>>1). So each 128-row staging half
// is consumed by exactly 2 quadrant phases and freed for same-dbuf restaging:
//   stage rotation: A1(T+1)@p0, B1(T+1)@p1 (other dbuf, freed since T-1);
//                   A0(T+2)@p2, B0(T+2)@p3 (this dbuf, LDS-freed after p0).
// Entry vmcnt(4) [counted, gloads] at each tile boundary confirms all 4 halves of the
// incoming tile (issued 3-6 phases earlier) while keeping p2/p3's 4 loads in flight.
// Per phase: {ds_reads 12/4/8/0 ; 1 half staged} BAR lgkm0+schb prio1 16xMFMA prio0 BAR.
// T2 swizzle: phys 16B-slot = logical ^ (row&7), source pre-permuted (sslot8).
__global__ __launch_bounds__(512) void gemm256(const u16* __restrict__ A, const u16* __restrict__ Bt,
                                               u16* __restrict__ Cout, int M, int N, int K) {
    __shared__ __attribute__((aligned(16))) u16 lds[65536];   // 2 dbuf x 4 halves x 8192
    int bid = blockIdx.x;
    int m0 = ((bid >> 3) & 7) * 256;
    int n0 = ((bid & 7) * 3 + (bid >> 6)) * 256;   // XCD j owns n-panels {3j..3j+2}
    int tid = threadIdx.x, lane = tid & 63, wid = tid >> 6;
    int wm = wid >> 2, wn = wid & 3;
    int l15 = lane & 15, g4 = lane >> 4;
    int sw = l15 & 7;
    int NK = K / 64;
    int sslot8 = ((tid & 7) ^ ((tid >> 3) & 7)) * 8;

    auto STAGE = [&](int kt, int half) {   // half: 0=A0,1=A1,2=B0,3=B1 (128 rows x 64 k)
#pragma unroll
        for (int c = 0; c < 2; ++c) {
            int row = c * 64 + (tid >> 3);
            const u16* src = (half < 2)
                ? &A[(size_t)(m0 + half * 128 + row) * K + kt * 64 + sslot8]
                : &Bt[(size_t)(n0 + (half - 2) * 128 + row) * K + kt * 64 + sslot8];
            gload16(src, &lds[(kt & 1) * 32768 + half * 8192 + c * 4096 + tid * 8]);
        }
    };

    f32x4 acc[8][4];
#pragma unroll
    for (int i = 0; i < 8; ++i)
#pragma unroll
        for (int j = 0; j < 4; ++j) acc[i][j] = (f32x4){0.f, 0.f, 0.f, 0.f};

    // prologue: halves in steady-state issue order
    STAGE(0, 0); STAGE(0, 2); STAGE(0, 1); STAGE(0, 3); STAGE(1, 0); STAGE(1, 2);
    VMC(4);   // confirms all of tile 0; A0(1),B0(1) stay in flight
    BAR(); SCHB();

    for (int T = 0; T < NK; ++T) {
        const u16* db = &lds[(T & 1) * 32768];
        bf16x8 a[8], b0[4], b1[4];

        // ---- p0 (q: mi 0-3 x nj 0-1): read A-half0 (8) + B-half0 (4); stage A1(T+1)
#pragma unroll
        for (int mi = 0; mi < 4; ++mi)
#pragma unroll
            for (int ks = 0; ks < 2; ++ks) {
                int r = mi * 32 + wm * 16 + l15;
                a[mi * 2 + ks] = *(const bf16x8*)&db[0 * 8192 + r * 64 + (((ks << 2) + g4) ^ sw) * 8];
            }
#pragma unroll
        for (int nj = 0; nj < 2; ++nj)
#pragma unroll
            for (int ks = 0; ks < 2; ++ks) {
                int r = nj * 64 + wn * 16 + l15;
                b0[nj * 2 + ks] = *(const bf16x8*)&db[2 * 8192 + r * 64 + (((ks << 2) + g4) ^ sw) * 8];
            }
        if (T + 1 < NK) STAGE(T + 1, 1);
        BAR(); LGKM0(); SCHB();
        __builtin_amdgcn_s_setprio(1);
#pragma unroll
        for (int mi = 0; mi < 4; ++mi)
#pragma unroll
            for (int nj = 0; nj < 2; ++nj)
#pragma unroll
                for (int ks = 0; ks < 2; ++ks)
                    acc[mi][nj] = __builtin_amdgcn_mfma_f32_16x16x32_bf16(a[mi * 2 + ks], b0[nj * 2 + ks], acc[mi][nj], 0, 0, 0);
        __builtin_amdgcn_s_setprio(0);
        BAR();

        // ---- p1 (mi 0-3 x nj 2-3): read B-half1 (4); stage B1(T+1)
#pragma unroll
        for (int nj = 0; nj < 2; ++nj)
#pragma unroll
            for (int ks = 0; ks < 2; ++ks) {
                int r = nj * 64 + wn * 16 + l15;
                b1[nj * 2 + ks] = *(const bf16x8*)&db[3 * 8192 + r * 64 + (((ks << 2) + g4) ^ sw) * 8];
            }
        if (T + 1 < NK) STAGE(T + 1, 3);
        BAR(); LGKM0(); SCHB();
        __builtin_amdgcn_s_setprio(1);
#pragma unroll
        for (int mi = 0; mi < 4; ++mi)
#pragma unroll
            for (int nj = 0; nj < 2; ++nj)
#pragma unroll
                for (int ks = 0; ks < 2; ++ks)
                    acc[mi][2 + nj] = __builtin_amdgcn_mfma_f32_16x16x32_bf16(a[mi * 2 + ks], b1[nj * 2 + ks], acc[mi][2 + nj], 0, 0, 0);
        __builtin_amdgcn_s_setprio(0);
        BAR();

        // ---- p2 (mi 4-7 x nj 0-1): read A-half1 (8); stage A0(T+2) into freed half
#pragma unroll
        for (int mi = 0; mi < 4; ++mi)
#pragma unroll
            for (int ks = 0; ks < 2; ++ks) {
                int r = mi * 32 + wm * 16 + l15;
                a[mi * 2 + ks] = *(const bf16x8*)&db[1 * 8192 + r * 64 + (((ks << 2) + g4) ^ sw) * 8];
            }
        if (T + 2 < NK) STAGE(T + 2, 0);
        BAR(); LGKM0(); SCHB();
        __builtin_amdgcn_s_setprio(1);
#pragma unroll
        for (int mi = 0; mi < 4; ++mi)
#pragma unroll
            for (int nj = 0; nj < 2; ++nj)
#pragma unroll
                for (int ks = 0; ks < 2; ++ks)
                    acc[4 + mi][nj] = __builtin_amdgcn_mfma_f32_16x16x32_bf16(a[mi * 2 + ks], b0[nj * 2 + ks], acc[4 + mi][nj], 0, 0, 0);
        __builtin_amdgcn_s_setprio(0);
        BAR();

        // ---- p3 (mi 4-7 x nj 2-3): no reads; stage B0(T+2); counted boundary vmcnt
        if (T + 2 < NK) STAGE(T + 2, 2);
        BAR();
        __builtin_amdgcn_s_setprio(1);
#pragma unroll
        for (int mi = 0; mi < 4; ++mi)
#pragma unroll
            for (int nj = 0; nj < 2; ++nj)
#pragma unroll
                for (int ks = 0; ks < 2; ++ks)
                    acc[4 + mi][2 + nj] = __builtin_amdgcn_mfma_f32_16x16x32_bf16(a[mi * 2 + ks], b1[nj * 2 + ks], acc[4 + mi][2 + nj], 0, 0, 0);
        __builtin_amdgcn_s_setprio(0);
        if (T + 2 < NK) VMC(4); else VMC(0);
        BAR(); SCHB();
    }

#pragma unroll
    for (int mi = 0; mi < 8; ++mi)
#pragma unroll
        for (int nj = 0; nj < 4; ++nj)
#pragma unroll
            for (int i = 0; i < 4; ++i) {
                int row = m0 + (mi >> 2) * 128 + (mi & 3) * 32 + wm * 16 + g4 * 4 + i;
                int col = n0 + (nj >> 1) * 128 + (nj & 1) * 64 + wn * 16 + l15;
                Cout[(size_t)row * N + col] = f2bf(acc[mi][nj][i]);
            }
}

// ---------------- pipelined GEMM (R9): BM=128 BK=64, for WO ----------------
// XCD-cluster mapping: XCD j owns 16m x 2n.
template <int BN, int OUTF32>
__global__ __launch_bounds__(512) void gemm4p(const u16* __restrict__ A, const u16* __restrict__ Bt,
                                              void* __restrict__ Cout, int M, int N, int K) {
    constexpr int NF = BN / 64;
    constexpr int LB = BN / 128;
    constexpr int DBUF = (128 + BN) * 64;
    constexpr int BHALF = (BN / 2) * 64;
    __shared__ __attribute__((aligned(16))) u16 lds[2 * DBUF];

    int bid = blockIdx.x;
    int m0 = ((bid >> 3) & 15) * 128;
    int n0 = ((bid & 7) * 2 + (bid >> 7)) * BN;
    int tid = threadIdx.x, lane = tid & 63, wid = tid >> 6;
    int wm = wid >> 2, wn = wid & 3;
    int l15 = lane & 15, g4 = lane >> 4;
    int sw = l15 & 7;
    int srow = tid >> 3;
    int sslot8 = (((tid & 7) ^ ((tid >> 3) & 7))) * 8;
    int brow0 = (wn & 1) * (BN / 4);
    int NK = K / 64;

    auto STAGE_A = [&](int kt, int h) {
        gload16(&A[(size_t)(m0 + h * 64 + srow) * K + kt * 64 + sslot8],
                &lds[(kt & 1) * DBUF + h * 4096 + wid * 512]);
    };
    auto STAGE_B = [&](int kt, int bh) {
#pragma unroll
        for (int it = 0; it < LB; ++it)
            gload16(&Bt[(size_t)(n0 + bh * (BN / 2) + it * 64 + srow) * K + kt * 64 + sslot8],
                    &lds[(kt & 1) * DBUF + 8192 + bh * BHALF + it * 4096 + wid * 512]);
    };

    f32x4 acc[4][NF];
#pragma unroll
    for (int i = 0; i < 4; ++i)
#pragma unroll
        for (int j = 0; j < NF; ++j) acc[i][j] = (f32x4){0.f, 0.f, 0.f, 0.f};

    STAGE_A(0, 0); STAGE_A(0, 1); STAGE_B(0, 0); STAGE_B(0, 1);
    STAGE_A(1, 0); STAGE_A(1, 1); STAGE_B(1, 0); STAGE_B(1, 1);
    VMC(2 + 2 * LB);
    BAR(); SCHB();

    for (int g = 0; g < NK; ++g) {
        const u16* dd = &lds[(g & 1) * DBUF];
        const u16* aw = dd + wm * 4096;
        const u16* bw = dd + 8192 + (wn >> 1) * BHALF;
        bool mid = (g > 0) && (g + 1 < NK);
        bf16x8 bfr[NF], af0, af1;

#pragma unroll
        for (int nf = 0; nf < NF; ++nf)
            bfr[nf] = *(const bf16x8*)&bw[(brow0 + nf * 16 + l15) * 64 + ((g4 ^ sw) * 8)];
        af0 = *(const bf16x8*)&aw[(0 * 16 + l15) * 64 + ((g4 ^ sw) * 8)];
        af1 = *(const bf16x8*)&aw[(1 * 16 + l15) * 64 + ((g4 ^ sw) * 8)];
        if (mid) STAGE_A(g + 1, 0);
        BAR(); LGKM0();
        __builtin_amdgcn_s_setprio(1);
#pragma unroll
        for (int nf = 0; nf < NF; ++nf) {
            acc[0][nf] = __builtin_amdgcn_mfma_f32_16x16x32_bf16(af0, bfr[nf], acc[0][nf], 0, 0, 0);
            acc[1][nf] = __builtin_amdgcn_mfma_f32_16x16x32_bf16(af1, bfr[nf], acc[1][nf], 0, 0, 0);
        }
        __builtin_amdgcn_s_setprio(0);
        BAR();

        af0 = *(const bf16x8*)&aw[(2 * 16 + l15) * 64 + ((g4 ^ sw) * 8)];
        af1 = *(const bf16x8*)&aw[(3 * 16 + l15) * 64 + ((g4 ^ sw) * 8)];
        if (mid) STAGE_B(g + 1, 1);
        BAR(); LGKM0();
        __builtin_amdgcn_s_setprio(1);
#pragma unroll
        for (int nf = 0; nf < NF; ++nf) {
            acc[2][nf] = __builtin_amdgcn_mfma_f32_16x16x32_bf16(af0, bfr[nf], acc[2][nf], 0, 0, 0);
            acc[3][nf] = __builtin_amdgcn_mfma_f32_16x16x32_bf16(af1, bfr[nf], acc[3][nf], 0, 0, 0);
        }
        __builtin_amdgcn_s_setprio(0);
        BAR();

#pragma unroll
        for (int nf = 0; nf < NF; ++nf)
            bfr[nf] = *(const bf16x8*)&bw[(brow0 + nf * 16 + l15) * 64 + (((4 + g4) ^ sw) * 8)];
        af0 = *(const bf16x8*)&aw[(0 * 16 + l15) * 64 + (((4 + g4) ^ sw) * 8)];
        af1 = *(const bf16x8*)&aw[(1 * 16 + l15) * 64 + (((4 + g4) ^ sw) * 8)];
        if (mid) STAGE_A(g + 1, 1);
        BAR(); LGKM0();
        __builtin_amdgcn_s_setprio(1);
#pragma unroll
        for (int nf = 0; nf < NF; ++nf) {
            acc[0][nf] = __builtin_amdgcn_mfma_f32_16x16x32_bf16(af0, bfr[nf], acc[0][nf], 0, 0, 0);
            acc[1][nf] = __builtin_amdgcn_mfma_f32_16x16x32_bf16(af1, bfr[nf], acc[1][nf], 0, 0, 0);
        }
        __builtin_amdgcn_s_setprio(0);
        BAR();

        af0 = *(const bf16x8*)&aw[(2 * 16 + l15) * 64 + (((4 + g4) ^ sw) * 8)];
        af1 = *(const bf16x8*)&aw[(3 * 16 + l15) * 64 + (((4 + g4) ^ sw) * 8)];
        if (g + 2 < NK) STAGE_B(g + 2, 0);
        BAR(); LGKM0();
        __builtin_amdgcn_s_setprio(1);
#pragma unroll
        for (int nf = 0; nf < NF; ++nf) {
            acc[2][nf] = __builtin_amdgcn_mfma_f32_16x16x32_bf16(af0, bfr[nf], acc[2][nf], 0, 0, 0);
            acc[3][nf] = __builtin_amdgcn_mfma_f32_16x16x32_bf16(af1, bfr[nf], acc[3][nf], 0, 0, 0);
        }
        __builtin_amdgcn_s_setprio(0);
        if (g <= NK - 3)      VMC(LB);
        else if (g == NK - 2) VMC(0);
        BAR(); SCHB();
    }

#pragma unroll
    for (int mf = 0; mf < 4; ++mf)
#pragma unroll
        for (int nf = 0; nf < NF; ++nf)
#pragma unroll
            for (int i = 0; i < 4; ++i) {
                int row = m0 + wm * 64 + mf * 16 + g4 * 4 + i;
                int col = n0 + wn * (BN / 4) + nf * 16 + l15;
                float v = acc[mf][nf][i];
                if (OUTF32) ((float*)Cout)[(size_t)row * N + col] = v;
                else        ((u16*)Cout)[(size_t)row * N + col] = f2bf(v);
            }
}

// ------ RoPE in-place on q,k slices (bf16), LDS trig table; Q pre-scaled by 1/sqrt(d) ------
__global__ __launch_bounds__(256) void ropek(u16* __restrict__ qkvb, const int* __restrict__ positions) {
    __shared__ float cs_[64], sn_[64];
    int t = blockIdx.x;
    float pos = (float)positions[t];
    if (threadIdx.x < 64) {
        int d = threadIdx.x;
        float inv = exp2f(-(float)d * (19.931568569324174f / 64.0f));
        float fr = pos * inv;
        cs_[d] = cosf(fr);
        sn_[d] = sinf(fr);
    }
    __syncthreads();
#pragma unroll
    for (int it = 0; it < 10; ++it) {
        int ci = it * 256 + threadIdx.x;
        int hh = ci >> 6, d = ci & 63;
        int base = (hh < NH) ? hh * HD : KOFF + (hh - NH) * HD;
        size_t off = (size_t)t * QKVN + base + d;
        float x1 = bf2f(qkvb[off]);
        float x2 = bf2f(qkvb[off + 64]);
        float s = sn_[d], c = cs_[d];
        float y1 = x1 * c - x2 * s;
        float y2 = x2 * c + x1 * s;
        if (hh < NH) { y1 *= ATTN_SCALE; y2 *= ATTN_SCALE; }
        qkvb[off]      = f2bf(y1);
        qkvb[off + 64] = f2bf(y2);
    }
}

// ---------------- V^T materialization: qkv v-slice -> vT[NKV][HD][T] ----------------
__global__ __launch_bounds__(256) void vtranspk(const u16* __restrict__ qkvb, u16* __restrict__ vT) {
    __shared__ __attribute__((aligned(16))) u16 tile[64][136];
    int kvh = blockIdx.x, t0 = blockIdx.y * 64;
    int tid = threadIdx.x;
#pragma unroll
    for (int it = 0; it < 4; ++it) {
        int ci = it * 256 + tid;
        int r = ci >> 4, c8 = (ci & 15) * 8;
        *(bf16x8*)&tile[r][c8] = *(const bf16x8*)&qkvb[(size_t)(t0 + r) * QKVN + VOFF + kvh * HD + c8];
    }
    __syncthreads();
#pragma unroll
    for (int it = 0; it < 4; ++it) {
        int ci = it * 256 + tid;
        int d = ci >> 3, tc = (ci & 7) * 8;
        union { bf16x8 v; u16 u[8]; } o;
#pragma unroll
        for (int e = 0; e < 8; ++e) o.u[e] = tile[tc + e][d];
        *(bf16x8*)&vT[((size_t)kvh * HD + d) * T_TOK + t0 + tc] = o.v;
    }
}

// -------- Flash attention (R14 version): block = (head, 128 q rows), 8 waves x 16 rows --------
__global__ __launch_bounds__(512) void attnk(const u16* __restrict__ qkvb, const u16* __restrict__ vT,
                                             u16* __restrict__ attnb) {
    __shared__ __attribute__((aligned(16))) u16 kt_[64 * 132];
    __shared__ __attribute__((aligned(16))) u16 vt_[128 * 68];
    __shared__ __attribute__((aligned(16))) u16 pl_[8 * 16 * 68];
    int h = blockIdx.x, qt = 15 - blockIdx.y;
    int kvh = h >> 2;
    int q0 = qt * 128;
    int tid = threadIdx.x, lane = tid & 63, wid = tid >> 6;
    int l15 = lane & 15, g = lane >> 4;

    const u16* kbase = qkvb + KOFF + (size_t)kvh * HD;
    const u16* vbase = vT + (size_t)kvh * HD * T_TOK;

    bf16x8 qf[4];
    int qrow = q0 + wid * 16 + l15;
#pragma unroll
    for (int ks = 0; ks < 4; ++ks)
        qf[ks] = *(const bf16x8*)&qkvb[(size_t)qrow * QKVN + h * HD + ks * 32 + g * 8];

    f32x4 o[8];
#pragma unroll
    for (int df = 0; df < 8; ++df) o[df] = (f32x4){0.f, 0.f, 0.f, 0.f};
    float m_run[4], l_run[4];
#pragma unroll
    for (int i = 0; i < 4; ++i) { m_run[i] = -3.0e38f; l_run[i] = 0.f; }

    int NT = 2 * qt + 2;

    bf16x8 kreg[2], vreg[2];
#pragma unroll
    for (int it = 0; it < 2; ++it) {
        int gi = it * 512 + tid;
        kreg[it] = *(const bf16x8*)&kbase[(size_t)(gi >> 4) * QKVN + (gi & 15) * 8];
        vreg[it] = *(const bf16x8*)&vbase[(size_t)(gi >> 3) * T_TOK + (gi & 7) * 8];
    }
#pragma unroll
    for (int it = 0; it < 2; ++it) {
        int gi = it * 512 + tid;
        *(bf16x8*)&kt_[(gi >> 4) * 132 + (gi & 15) * 8] = kreg[it];
        *(bf16x8*)&vt_[(gi >> 3) * 68 + (gi & 7) * 8] = vreg[it];
    }
#pragma unroll
    for (int it = 0; it < 2; ++it) {
        int gi = it * 512 + tid;
        kreg[it] = *(const bf16x8*)&kbase[(size_t)(64 + (gi >> 4)) * QKVN + (gi & 15) * 8];
        vreg[it] = *(const bf16x8*)&vbase[(size_t)(gi >> 3) * T_TOK + 64 + (gi & 7) * 8];
    }
    __syncthreads();

    for (int kt2 = 0; kt2 < NT; ++kt2) {
        int kvb = kt2 * 64;
        bool active = (kvb <= q0 + wid * 16 + 15);
        bool diag   = (kvb + 63 > q0 + wid * 16);

        if (active) {
            f32x4 s[4];
#pragma unroll
            for (int nf = 0; nf < 4; ++nf) s[nf] = (f32x4){0.f, 0.f, 0.f, 0.f};
            __builtin_amdgcn_s_setprio(1);
#pragma unroll
            for (int ks = 0; ks < 4; ++ks) {
#pragma unroll
                for (int nf = 0; nf < 4; ++nf) {
                    bf16x8 bfr = *(const bf16x8*)&kt_[(nf * 16 + l15) * 132 + ks * 32 + g * 8];
                    s[nf] = __builtin_amdgcn_mfma_f32_16x16x32_bf16(qf[ks], bfr, s[nf], 0, 0, 0);
                }
            }
            __builtin_amdgcn_s_setprio(0);

            float mloc[4];
#pragma unroll
            for (int i = 0; i < 4; ++i) {
                int qr = q0 + wid * 16 + g * 4 + i;
                float mx = -3.0e38f;
#pragma unroll
                for (int nf = 0; nf < 4; ++nf) {
                    float v = s[nf][i];
                    if (diag) {
                        int kvc = kvb + nf * 16 + l15;
                        v = (kvc <= qr) ? v : -1.0e30f;
                        s[nf][i] = v;
                    }
                    mx = fmaxf(mx, v);
                }
                mloc[i] = mx;
            }

            int ok = 1;
#pragma unroll
            for (int i = 0; i < 4; ++i) ok &= (mloc[i] <= m_run[i] + 8.0f) ? 1 : 0;
            if (!__all(ok)) {
                float mrow[4];
#pragma unroll
                for (int i = 0; i < 4; ++i) mrow[i] = mloc[i];
#pragma unroll
                for (int dd = 1; dd < 16; dd <<= 1)
#pragma unroll
                    for (int i = 0; i < 4; ++i) mrow[i] = fmaxf(mrow[i], __shfl_xor(mrow[i], dd));
                float alpha[4];
#pragma unroll
                for (int i = 0; i < 4; ++i) {
                    float mnew = fmaxf(m_run[i], mrow[i]);
                    alpha[i] = __expf(m_run[i] - mnew);
                    m_run[i] = mnew;
                    l_run[i] *= alpha[i];
                }
#pragma unroll
                for (int df = 0; df < 8; ++df)
#pragma unroll
                    for (int i = 0; i < 4; ++i) o[df][i] *= alpha[i];
            }

#pragma unroll
            for (int nf = 0; nf < 4; ++nf)
#pragma unroll
                for (int i = 0; i < 4; ++i) {
                    float p = __expf(s[nf][i] - m_run[i]);
                    l_run[i] += p;
                    pl_[wid * 1088 + (g * 4 + i) * 68 + nf * 16 + l15] = f2bf(p);
                }

            __builtin_amdgcn_s_setprio(1);
#pragma unroll
            for (int ks2 = 0; ks2 < 2; ++ks2) {
                bf16x8 af = *(const bf16x8*)&pl_[wid * 1088 + l15 * 68 + ks2 * 32 + g * 8];
#pragma unroll
                for (int df = 0; df < 8; ++df) {
                    bf16x8 bfr = *(const bf16x8*)&vt_[(df * 16 + l15) * 68 + ks2 * 32 + g * 8];
                    o[df] = __builtin_amdgcn_mfma_f32_16x16x32_bf16(af, bfr, o[df], 0, 0, 0);
                }
            }
            __builtin_amdgcn_s_setprio(0);
        }

        if (kt2 < NT - 1) {
            __syncthreads();
#pragma unroll
            for (int it = 0; it < 2; ++it) {
                int gi = it * 512 + tid;
                *(bf16x8*)&kt_[(gi >> 4) * 132 + (gi & 15) * 8] = kreg[it];
                *(bf16x8*)&vt_[(gi >> 3) * 68 + (gi & 7) * 8] = vreg[it];
            }
            int ktl = (kt2 + 2 < NT) ? kt2 + 2 : NT - 1;
#pragma unroll
            for (int it = 0; it < 2; ++it) {
                int gi = it * 512 + tid;
                kreg[it] = *(const bf16x8*)&kbase[(size_t)(ktl * 64 + (gi >> 4)) * QKVN + (gi & 15) * 8];
                vreg[it] = *(const bf16x8*)&vbase[(size_t)(gi >> 3) * T_TOK + ktl * 64 + (gi & 7) * 8];
            }
            __syncthreads();
        }
    }

#pragma unroll
    for (int dd = 1; dd < 16; dd <<= 1)
#pragma unroll
        for (int i = 0; i < 4; ++i) l_run[i] += __shfl_xor(l_run[i], dd);

#pragma unroll
    for (int df = 0; df < 8; ++df)
#pragma unroll
        for (int i = 0; i < 4; ++i) {
            int qr = q0 + wid * 16 + g * 4 + i;
            int col = h * HD + df * 16 + l15;
            attnb[(size_t)qr * (NH * HD) + col] = f2bf(o[df][i] / l_run[i]);
        }
}

extern "C" void kernel_launch(void* const* d_in, const int* in_sizes, int n_in,
                              void* d_out, int out_size, void* d_ws, size_t ws_size,
                              hipStream_t stream) {
    const int*   positions = (const int*)d_in[0];
    const float* hs        = (const float*)d_in[1];
    const float* wqkv      = (const float*)d_in[2];
    const float* wo        = (const float*)d_in[3];
    float* out = (float*)d_out;

    char* ws = (char*)d_ws;
    u16* hsb   = (u16*)(ws);                                   // 16,777,216  (reused as attnb)
    u16* wqkvT = (u16*)(ws + 16777216);                        // 50,331,648
    u16* woT   = (u16*)(ws + 16777216 + 50331648);             // 33,554,432
    u16* qkvb  = (u16*)(ws + 16777216 + 50331648 + 33554432);  // 25,165,824
    u16* vT    = (u16*)(ws + 16777216 + 50331648 + 33554432 + 25165824); // 4,194,304
    u16* attnb = hsb;

    convk<<<8192, 256, 0, stream>>>(hs, hsb);
    transpk<<<dim3(96, 64), 256, 0, stream>>>(wqkv, wqkvT, HID, QKVN);
    transpk<<<dim3(64, 64), 256, 0, stream>>>(wo, woT, HID, HID);

    // QKV GEMM: m201-style 256x256, grid 8m x 24n = 192 blocks (XCD owns 8m x 3n)
    gemm256<<<dim3(192), 512, 0, stream>>>(hsb, wqkvT, qkvb, T_TOK, QKVN, HID);

    ropek<<<T_TOK, 256, 0, stream>>>(qkvb, positions);

    vtranspk<<<dim3(NKV, 32), 256, 0, stream>>>(qkvb, vT);

    // attention: 128-row q tiles, 8 waves x 16 rows, 512 blocks
    attnk<<<dim3(NH, 16), 512, 0, stream>>>(qkvb, vT, attnb);

    // WO GEMM: BM=128 BN=256, XCD-cluster mapping (16m x 2n per XCD), 256 blocks
    gemm4p<256, 1><<<dim3(256), 512, 0, stream>>>(attnb, woT, out, T_TOK, HID, HID);
}